// Round 2
// baseline (6057.425 us; speedup 1.0000x reference)
//
#include <hip/hip_runtime.h>

// ---------------------------------------------------------------------------
// SimpleLSTM: 2-layer LSTM (B=32,T=512,D=512,H=1024) + output proj (O=512).
//   conv kernels : fp32 -> f16, weights rearranged into MFMA B-frag order
//   zx0_gemm     : Zx0[t][wg][m][c] = x@Wx0 + b0  (parallel over all T)
//   lstm_persist : 256 persistent WGs (1/CU), recurrent weights in LDS
//   wd_gemm      : Y = H1 @ Wd + bd
// R4: tree barrier, 1 barrier/step (22.7 -> 14.5 ms).
// R5: uncached h-exchange stores, direct-from-global A-frags (14.5 -> 8.3).
// R6: poll de-congestion + merged B(t)/A(t+1) phase (8.3 -> 7.6).
// R7: NO FENCES. h1a t-indexed; fresh-line reads need no invalidate (7.6->6.6).
// R8: h0a t-indexed too; all h reads plain cached loads (6.6 -> 5.8).
// R9: FLAT BARRIER, ZERO RMWs. The R4 tree put 3 serialized levels of
//     contended LLC fetch_adds (8/leaf-line, 32 on ONE root line) plus a
//     32-store serial broadcast on the post-last-arrival critical path,
//     executed by the slowest WG. Replaced with: 256 single-writer done[]
//     slots (packed 1 KiB, plain uncached stores) + WG0-wave0 checker that
//     polls all 256 slots with 2xb64/lane (8 lines/round) and broadcasts
//     256 private go lines with 4 stores/lane. No atomics RMW anywhere,
//     broadcast issues in parallel, checker is already polling when the
//     last producer's store lands.
// ---------------------------------------------------------------------------

typedef _Float16 half8  __attribute__((ext_vector_type(8)));
typedef float    floatx4 __attribute__((ext_vector_type(4)));

// ws layout (bytes)
#define WREC_OFF   0UL            // [256 wg][3 mat][128 kc][16 c][8] f16 = 24 MiB
#define WX0_OFF    25165824UL     // [256 wg][64 kc][16 c][8] f16        = 4 MiB
#define WD_OFF     29360128UL     // [32 nt][128 kc][16 c][8] f16        = 1 MiB
#define XH_OFF     30408704UL     // [512 t][32 b][512 d] f16            = 16 MiB
#define ZX0_OFF    47185920UL     // [512 t][256 wg][32 m][16 c] f16     = 128 MiB
#define H1_OFF     181403648UL    // [512 t][32 m][1024 k] f16           = 32 MiB
#define H0_OFF     214958080UL    // [512 t][32 m][1024 k] f16           = 32 MiB
#define FLAGS_OFF  248512512UL    // 72 KiB: done[256]x4B @0, go[256]@256B @8192

__device__ __forceinline__ float fsig(float x){ return 1.0f/(1.0f + __expf(-x)); }
__device__ __forceinline__ float ftanhf(float x){
  float e = __expf(2.0f*fabsf(x));
  float r = 1.0f - 2.0f/(e + 1.0f);
  return copysignf(r, x);
}

// ---------------- weight conversion ----------------------------------------
__global__ void conv_wrec(const float* __restrict__ Wh0,
                          const float* __restrict__ Wx1,
                          const float* __restrict__ Wh1,
                          _Float16* __restrict__ out){
  int idx = blockIdx.x*256 + threadIdx.x;          // ((wg*3+mat)*128+kc)*16+c
  if (idx >= 256*3*128*16) return;
  int c  = idx & 15;
  int t1 = idx >> 4;
  int kc = t1 & 127;
  int t2 = t1 >> 7;
  int mat = t2 % 3;
  int wg  = t2 / 3;
  const float* W = (mat==0) ? Wh0 : (mat==1) ? Wx1 : Wh1;
  int col = (c>>2)*1024 + wg*4 + (c&3);
  _Float16* o = out + (size_t)idx*8;
  #pragma unroll
  for (int j=0;j<8;++j) o[j] = (_Float16)W[(kc*8+j)*4096 + col];
}

__global__ void conv_wx0(const float* __restrict__ W, _Float16* __restrict__ out){
  int idx = blockIdx.x*256 + threadIdx.x;          // ((wg*64+kc)*16+c)
  if (idx >= 256*64*16) return;
  int c  = idx & 15;
  int kc = (idx >> 4) & 63;
  int wg = idx >> 10;
  int col = (c>>2)*1024 + wg*4 + (c&3);
  _Float16* o = out + (size_t)idx*8;
  #pragma unroll
  for (int j=0;j<8;++j) o[j] = (_Float16)W[(kc*8+j)*4096 + col];
}

__global__ void conv_wd(const float* __restrict__ W, _Float16* __restrict__ out){
  int idx = blockIdx.x*256 + threadIdx.x;          // ((nt*128+kc)*16+c)
  if (idx >= 32*128*16) return;
  int c  = idx & 15;
  int kc = (idx >> 4) & 127;
  int nt = idx >> 11;
  int col = nt*16 + c;
  _Float16* o = out + (size_t)idx*8;
  #pragma unroll
  for (int j=0;j<8;++j) o[j] = (_Float16)W[(kc*8+j)*512 + col];
}

// x[b][t][d] fp32 -> xh[t*32+b][d] f16  (time-major rows for zx0_gemm)
__global__ void conv_x(const float* __restrict__ x, _Float16* __restrict__ xh){
  int idx = blockIdx.x*256 + threadIdx.x;          // [bt][dq], dq = d/4
  if (idx >= 2097152) return;
  int dq = idx & 127;
  int bt = idx >> 7;          // t*32 + b
  int b  = bt & 31;
  int t  = bt >> 5;
  float4 v = ((const float4*)x)[(size_t)(b*512 + t)*128 + dq];
  _Float16* o = xh + (size_t)idx*4;
  o[0]=(_Float16)v.x; o[1]=(_Float16)v.y; o[2]=(_Float16)v.z; o[3]=(_Float16)v.w;
}

// ---------------- Zx0 = x @ Wx0 + b0 ---------------------------------------
__global__ __launch_bounds__(64) void zx0_gemm(const _Float16* __restrict__ xh,
                                               const _Float16* __restrict__ wx0a,
                                               const float* __restrict__ b0,
                                               _Float16* __restrict__ zx0){
  int t   = blockIdx.x;        // 512
  int wgg = blockIdx.y;        // 64 (covers 4 wg slices)
  int l = threadIdx.x, q = l>>4, c = l&15;
  floatx4 acc[2][4];
  #pragma unroll
  for (int g=0; g<4; ++g){
    int wg = wgg*4+g;
    float bv = b0[(c>>2)*1024 + wg*4 + (c&3)];
    acc[0][g] = (floatx4){bv,bv,bv,bv};
    acc[1][g] = (floatx4){bv,bv,bv,bv};
  }
  #pragma unroll 4
  for (int ks=0; ks<16; ++ks){
    int kc = ks*4 + q;
    half8 a0 = *(const half8*)(xh + (t*32      + c)*512 + kc*8);
    half8 a1 = *(const half8*)(xh + (t*32 + 16 + c)*512 + kc*8);
    #pragma unroll
    for (int g=0; g<4; ++g){
      int wg = wgg*4+g;
      half8 b = *(const half8*)(wx0a + ((size_t)(wg*64 + kc)*16 + c)*8);
      acc[0][g] = __builtin_amdgcn_mfma_f32_16x16x32_f16(a0,b,acc[0][g],0,0,0);
      acc[1][g] = __builtin_amdgcn_mfma_f32_16x16x32_f16(a1,b,acc[1][g],0,0,0);
    }
  }
  #pragma unroll
  for (int g=0; g<4; ++g){
    int wg = wgg*4+g;
    #pragma unroll
    for (int mt=0; mt<2; ++mt)
      #pragma unroll
      for (int r=0;r<4;++r){
        int m = mt*16 + q*4 + r;
        zx0[((size_t)(t*256 + wg)*32 + m)*16 + c] = (_Float16)acc[mt][g][r];
      }
  }
}

// ---------------- persistent recurrent kernel ------------------------------
// LDS: w0 (Wh0), w1 (Wx1), w2 (Wh1): [128 kc][16 c][8] each = 96 KiB total
#define AF(base, ks)  (*(const half8*)((base) + (ks)*32))
#define BF(w, ks)     (*(const half8*)((w) + (((ks)*4 + q)*16 + c)*8))

// gate exchange + cell update + packed agent-scope store of h (cols wg*4..+3)
__device__ __forceinline__ void gates_store(floatx4 acc, float* cs,
    _Float16* dst, int g, int c, int mt, int q, int wg){
  #pragma unroll
  for (int r=0;r<4;++r){
    float v0 = acc[r];
    float v1 = __shfl_xor(v0, 4, 64);
    float v2 = __shfl_xor(v0, 8, 64);
    float v3 = __shfl_xor(v1, 8, 64);
    float zi = (g==0)?v0:(g==1)?v1:(g==2)?v2:v3;
    float zf = (g==0)?v1:(g==1)?v0:(g==2)?v3:v2;
    float zg = (g==0)?v2:(g==1)?v3:(g==2)?v0:v1;
    float zo = (g==0)?v3:(g==1)?v2:(g==2)?v1:v0;
    float cn = fsig(zf)*cs[r] + fsig(zi)*ftanhf(zg);
    cs[r] = cn;
    float hv = fsig(zo)*ftanhf(cn);
    unsigned hb16 = (unsigned)__builtin_bit_cast(unsigned short, (_Float16)hv);
    unsigned up   = (unsigned)__shfl_xor((int)hb16, 1, 64);
    if (g==0 && (c&1)==0)
      __hip_atomic_store((unsigned*)(dst + (mt*16 + q*4 + r)*1024 + wg*4 + c),
                         hb16 | (up<<16),
                         __ATOMIC_RELAXED, __HIP_MEMORY_SCOPE_AGENT);
  }
}

__global__ __launch_bounds__(128, 1) void lstm_persist(
    const _Float16* __restrict__ wrec, const _Float16* __restrict__ zx0,
    const float* __restrict__ b1g, _Float16* __restrict__ h0a,
    _Float16* __restrict__ h1a, unsigned int* __restrict__ flags)
{
  extern __shared__ _Float16 lds[];
  _Float16* w0  = lds;            // 16384 halves
  _Float16* w1  = lds + 16384;
  _Float16* w2  = lds + 32768;

  const int wg = blockIdx.x, tid = threadIdx.x;
  const int wv = tid>>6, l = tid&63, q = l>>4, c = l&15;
  const int g = (c>>2);           // gate of own column
  const int mt = wv;              // wave0 rows 0-15, wave1 rows 16-31
  const int row = mt*16 + c;      // A-frag row this lane loads

  unsigned int* done = flags;                 // 256 x u32, packed (8 lines)
  unsigned int* go   = flags + 2048;          // go[wg] at +wg*64 (256B stride)

  { // stage this WG's weight slice: 98304 B = 6144 uint4
    const uint4* src = (const uint4*)(wrec + (size_t)wg*49152);
    uint4* dst = (uint4*)lds;
    for (int i=tid; i<6144; i+=128) dst[i] = src[i];
  }
  float c0[4] = {0,0,0,0}, c1[4] = {0,0,0,0};
  const float b1v = b1g[g*1024 + wg*4 + (c&3)];
  __syncthreads();

  // ---------- prologue: A(0): h0(0) = act(Zx0[0]) (h0(-1)=0) ----------
  {
    const _Float16* zsrc = zx0 + ((size_t)wg*32 + mt*16 + q*4)*16 + c;
    floatx4 a;
    a[0]=(float)zsrc[0]; a[1]=(float)zsrc[16]; a[2]=(float)zsrc[32]; a[3]=(float)zsrc[48];
    gates_store(a, c0, h0a, g, c, mt, q, wg);   // t = 0
  }

  for (int t=0; t<512; ++t){
    // prefetch zx0 for A(t+1) (register-resident across the barrier)
    int tn = (t<511) ? t+1 : 511;
    const _Float16* zsrc = zx0 + ((size_t)(tn*256 + wg)*32 + mt*16 + q*4)*16 + c;
    float pz0=(float)zsrc[0], pz1=(float)zsrc[16], pz2=(float)zsrc[32], pz3=(float)zsrc[48];

    __syncthreads();   // drains vmcnt: h0(t)/h1(t-1) stores visible at LLC

    // ---------- flat device barrier: no RMWs, parallel broadcast ----------
    const unsigned tgt = (unsigned)(t+1);
    if (wg == 0){
      if (wv == 0){
        if (l == 0)
          __hip_atomic_store(done, tgt, __ATOMIC_RELAXED, __HIP_MEMORY_SCOPE_AGENT);
        const unsigned long long* dp = (const unsigned long long*)done + (size_t)l*2;
        for (;;){
          unsigned long long v0 = __hip_atomic_load(dp,   __ATOMIC_RELAXED, __HIP_MEMORY_SCOPE_AGENT);
          unsigned long long v1 = __hip_atomic_load(dp+1, __ATOMIC_RELAXED, __HIP_MEMORY_SCOPE_AGENT);
          int ok = ((unsigned)v0 >= tgt) & ((unsigned)(v0>>32) >= tgt)
                 & ((unsigned)v1 >= tgt) & ((unsigned)(v1>>32) >= tgt);
          if (__ballot(ok) == 0xffffffffffffffffULL) break;
          __builtin_amdgcn_s_sleep(1);
        }
        #pragma unroll
        for (int k2=0; k2<4; ++k2)
          __hip_atomic_store(go + (size_t)(l*4+k2)*64, tgt,
                             __ATOMIC_RELAXED, __HIP_MEMORY_SCOPE_AGENT);
      }
    } else if (tid == 0){
      __hip_atomic_store(done + wg, tgt, __ATOMIC_RELAXED, __HIP_MEMORY_SCOPE_AGENT);
      while (__hip_atomic_load(go + (size_t)wg*64, __ATOMIC_RELAXED,
                               __HIP_MEMORY_SCOPE_AGENT) < tgt)
        __builtin_amdgcn_s_sleep(1);
    }
    __syncthreads();
    // NO acquire fence: h0a[t]/h1a[t-1] lines are fresh by construction
    // (never cached by any XCD before this read; producers stored uncached
    // to LLC). zx0/weights are read-only; __syncthreads orders compiler+HW.

    // ---------- merged compute: B(t) and A(t+1) ----------
    const _Float16* h0c = h0a + (size_t)t*32768 + row*1024 + q*8;
    floatx4 aA0={0,0,0,0}, aA1={0,0,0,0};
    floatx4 aB0={b1v,b1v,b1v,b1v}, aB1={0,0,0,0};
    floatx4 aC0={0,0,0,0}, aC1={0,0,0,0};
    if (t > 0){
      const _Float16* h1p = h1a + (size_t)(t-1)*32768 + row*1024 + q*8;
      #pragma unroll
      for (int s=0; s<16; ++s){
        aC0 = __builtin_amdgcn_mfma_f32_16x16x32_f16(AF(h1p,s),    BF(w2,s),    aC0,0,0,0);
        aC1 = __builtin_amdgcn_mfma_f32_16x16x32_f16(AF(h1p,16+s), BF(w2,16+s), aC1,0,0,0);
      }
    }
    #pragma unroll
    for (int s=0; s<16; ++s){
      half8 f0 = AF(h0c,s), f1 = AF(h0c,16+s);
      aB0 = __builtin_amdgcn_mfma_f32_16x16x32_f16(f0, BF(w1,s),    aB0,0,0,0);
      aB1 = __builtin_amdgcn_mfma_f32_16x16x32_f16(f1, BF(w1,16+s), aB1,0,0,0);
      aA0 = __builtin_amdgcn_mfma_f32_16x16x32_f16(f0, BF(w0,s),    aA0,0,0,0);
      aA1 = __builtin_amdgcn_mfma_f32_16x16x32_f16(f1, BF(w0,16+s), aA1,0,0,0);
    }
    // B(t): h1(t)
    {
      floatx4 z1 = (aB0+aB1)+(aC0+aC1);
      gates_store(z1, c1, h1a + (size_t)t*32768, g, c, mt, q, wg);
    }
    // A(t+1): h0(t+1)
    if (t < 511){
      floatx4 z0 = aA0+aA1;
      z0[0]+=pz0; z0[1]+=pz1; z0[2]+=pz2; z0[3]+=pz3;
      gates_store(z0, c0, h0a + (size_t)((t+1))*32768, g, c, mt, q, wg);
    }
  }
}

// ---------------- Y = H1 @ Wd + bd -----------------------------------------
__global__ __launch_bounds__(256) void wd_gemm(const _Float16* __restrict__ h1a,
                                               const _Float16* __restrict__ wda,
                                               const float* __restrict__ bd,
                                               float* __restrict__ y){
  int mb = blockIdx.x;   // 512 blocks of 32 rows (rows = t*32+b)
  int nb = blockIdx.y;   // 4 blocks of 128 cols
  int tid = threadIdx.x, wv = tid>>6, l = tid&63, q = l>>4, c = l&15;
  int mt = wv & 1, nh = wv >> 1;
  floatx4 acc[4];
  #pragma unroll
  for (int gg=0; gg<4; ++gg) acc[gg] = (floatx4){0.f,0.f,0.f,0.f};
  const _Float16* arow = h1a + (size_t)(mb*32 + mt*16 + c)*1024;
  #pragma unroll 4
  for (int ks=0; ks<32; ++ks){
    int kc = ks*4 + q;
    half8 a = *(const half8*)(arow + kc*8);
    #pragma unroll
    for (int gg=0; gg<4; ++gg){
      int nt = nb*8 + nh*4 + gg;
      half8 b = *(const half8*)(wda + ((size_t)(nt*128 + kc)*16 + c)*8);
      acc[gg] = __builtin_amdgcn_mfma_f32_16x16x32_f16(a,b,acc[gg],0,0,0);
    }
  }
  #pragma unroll
  for (int gg=0; gg<4; ++gg){
    int o = nb*128 + nh*64 + gg*16 + c;
    float bdv = bd[o];
    #pragma unroll
    for (int r=0;r<4;++r){
      int row = mb*32 + mt*16 + q*4 + r;
      int tt = row >> 5, bb = row & 31;
      y[(size_t)bb*262144 + tt*512 + o] = acc[gg][r] + bdv;
    }
  }
}

// ---------------------------------------------------------------------------
extern "C" void kernel_launch(void* const* d_in, const int* in_sizes, int n_in,
                              void* d_out, int out_size, void* d_ws, size_t ws_size,
                              hipStream_t stream){
  const float* x   = (const float*)d_in[0];
  const float* Wx0 = (const float*)d_in[1];
  const float* Wh0 = (const float*)d_in[2];
  const float* b0  = (const float*)d_in[3];
  const float* Wx1 = (const float*)d_in[4];
  const float* Wh1 = (const float*)d_in[5];
  const float* b1  = (const float*)d_in[6];
  const float* Wd  = (const float*)d_in[7];
  const float* bd  = (const float*)d_in[8];
  float* y = (float*)d_out;
  char* ws = (char*)d_ws;

  _Float16* wrec = (_Float16*)(ws + WREC_OFF);
  _Float16* wx0a = (_Float16*)(ws + WX0_OFF);
  _Float16* wda  = (_Float16*)(ws + WD_OFF);
  _Float16* xh   = (_Float16*)(ws + XH_OFF);
  _Float16* zx0  = (_Float16*)(ws + ZX0_OFF);
  _Float16* h1a  = (_Float16*)(ws + H1_OFF);
  _Float16* h0a  = (_Float16*)(ws + H0_OFF);
  unsigned int* flags = (unsigned int*)(ws + FLAGS_OFF);

  hipMemsetAsync(flags, 0, 73728, stream);
  conv_wrec<<<dim3(6144), dim3(256), 0, stream>>>(Wh0, Wx1, Wh1, wrec);
  conv_wx0 <<<dim3(1024), dim3(256), 0, stream>>>(Wx0, wx0a);
  conv_wd  <<<dim3(256),  dim3(256), 0, stream>>>(Wd, wda);
  conv_x   <<<dim3(8192), dim3(256), 0, stream>>>(x, xh);
  zx0_gemm <<<dim3(512,64), dim3(64), 0, stream>>>(xh, wx0a, b0, zx0);
  hipFuncSetAttribute((const void*)lstm_persist,
                      hipFuncAttributeMaxDynamicSharedMemorySize, 98304);
  lstm_persist<<<dim3(256), dim3(128), 98304, stream>>>(wrec, zx0, b1, h0a, h1a, flags);
  wd_gemm  <<<dim3(512,4), dim3(256), 0, stream>>>(h1a, wda, bd, y);
}

// Round 3
// 5113.223 us; speedup vs baseline: 1.1847x; 1.1847x over previous
//
#include <hip/hip_runtime.h>

// ---------------------------------------------------------------------------
// SimpleLSTM: 2-layer LSTM (B=32,T=512,D=512,H=1024) + output proj (O=512).
//   conv kernels : fp32 -> f16, weights rearranged into MFMA B-frag order
//   zx0_gemm     : Zx0[t][wg][m][c] = x@Wx0 + b0  (parallel over all T)
//   lstm_persist : 256 persistent WGs (1/CU), recurrent weights in LDS
//   wd_gemm      : Y = H1 @ Wd + bd
// R4: tree barrier, 1 barrier/step (22.7 -> 14.5 ms).
// R5: uncached h-exchange stores, direct-from-global A-frags (14.5 -> 8.3).
// R6: poll de-congestion + merged B(t)/A(t+1) phase (8.3 -> 7.6).
// R7: NO FENCES. h1a t-indexed; fresh-line reads need no invalidate (7.6->6.6).
// R8: h0a t-indexed too; all h reads plain cached loads (6.6 -> 5.8).
// R9: flat zero-RMW barrier — REGRESSED (5.4 -> 5.7 persist); barrier
//     micro-structure is not the lever. Reverted to R8 tree.
// R10: REGISTER-BATCHED h LOADS. R8/R9 codegen held only ~4-8 of the 64
//     independent 16B h-fragment loads in flight (VGPR_Count 52!), exposing
//     ~10-16 fresh-line LLC round trips (~230ns each) per step. Now all 32
//     h1 + 32 h0 fragments are loaded into fully-unrolled static half8
//     arrays (~256 VGPRs in flight, launch_bounds(128,1) permits 512/wave)
//     before the MFMA chains consume them; vmcnt retires in order so the
//     h1-consuming chain starts while h0 loads are still in flight.
// ---------------------------------------------------------------------------

typedef _Float16 half8  __attribute__((ext_vector_type(8)));
typedef float    floatx4 __attribute__((ext_vector_type(4)));

// ws layout (bytes)
#define WREC_OFF   0UL            // [256 wg][3 mat][128 kc][16 c][8] f16 = 24 MiB
#define WX0_OFF    25165824UL     // [256 wg][64 kc][16 c][8] f16        = 4 MiB
#define WD_OFF     29360128UL     // [32 nt][128 kc][16 c][8] f16        = 1 MiB
#define XH_OFF     30408704UL     // [512 t][32 b][512 d] f16            = 16 MiB
#define ZX0_OFF    47185920UL     // [512 t][256 wg][32 m][16 c] f16     = 128 MiB
#define H1_OFF     181403648UL    // [512 t][32 m][1024 k] f16           = 32 MiB
#define H0_OFF     214958080UL    // [512 t][32 m][1024 k] f16           = 32 MiB
#define FLAGS_OFF  248512512UL    // 24 KiB: gcnt[32]@256B, root, go[32]@256B

__device__ __forceinline__ float fsig(float x){ return 1.0f/(1.0f + __expf(-x)); }
__device__ __forceinline__ float ftanhf(float x){
  float e = __expf(2.0f*fabsf(x));
  float r = 1.0f - 2.0f/(e + 1.0f);
  return copysignf(r, x);
}

// ---------------- weight conversion ----------------------------------------
__global__ void conv_wrec(const float* __restrict__ Wh0,
                          const float* __restrict__ Wx1,
                          const float* __restrict__ Wh1,
                          _Float16* __restrict__ out){
  int idx = blockIdx.x*256 + threadIdx.x;          // ((wg*3+mat)*128+kc)*16+c
  if (idx >= 256*3*128*16) return;
  int c  = idx & 15;
  int t1 = idx >> 4;
  int kc = t1 & 127;
  int t2 = t1 >> 7;
  int mat = t2 % 3;
  int wg  = t2 / 3;
  const float* W = (mat==0) ? Wh0 : (mat==1) ? Wx1 : Wh1;
  int col = (c>>2)*1024 + wg*4 + (c&3);
  _Float16* o = out + (size_t)idx*8;
  #pragma unroll
  for (int j=0;j<8;++j) o[j] = (_Float16)W[(kc*8+j)*4096 + col];
}

__global__ void conv_wx0(const float* __restrict__ W, _Float16* __restrict__ out){
  int idx = blockIdx.x*256 + threadIdx.x;          // ((wg*64+kc)*16+c)
  if (idx >= 256*64*16) return;
  int c  = idx & 15;
  int kc = (idx >> 4) & 63;
  int wg = idx >> 10;
  int col = (c>>2)*1024 + wg*4 + (c&3);
  _Float16* o = out + (size_t)idx*8;
  #pragma unroll
  for (int j=0;j<8;++j) o[j] = (_Float16)W[(kc*8+j)*4096 + col];
}

__global__ void conv_wd(const float* __restrict__ W, _Float16* __restrict__ out){
  int idx = blockIdx.x*256 + threadIdx.x;          // ((nt*128+kc)*16+c)
  if (idx >= 32*128*16) return;
  int c  = idx & 15;
  int kc = (idx >> 4) & 127;
  int nt = idx >> 11;
  int col = nt*16 + c;
  _Float16* o = out + (size_t)idx*8;
  #pragma unroll
  for (int j=0;j<8;++j) o[j] = (_Float16)W[(kc*8+j)*512 + col];
}

// x[b][t][d] fp32 -> xh[t*32+b][d] f16  (time-major rows for zx0_gemm)
__global__ void conv_x(const float* __restrict__ x, _Float16* __restrict__ xh){
  int idx = blockIdx.x*256 + threadIdx.x;          // [bt][dq], dq = d/4
  if (idx >= 2097152) return;
  int dq = idx & 127;
  int bt = idx >> 7;          // t*32 + b
  int b  = bt & 31;
  int t  = bt >> 5;
  float4 v = ((const float4*)x)[(size_t)(b*512 + t)*128 + dq];
  _Float16* o = xh + (size_t)idx*4;
  o[0]=(_Float16)v.x; o[1]=(_Float16)v.y; o[2]=(_Float16)v.z; o[3]=(_Float16)v.w;
}

// ---------------- Zx0 = x @ Wx0 + b0 ---------------------------------------
__global__ __launch_bounds__(64) void zx0_gemm(const _Float16* __restrict__ xh,
                                               const _Float16* __restrict__ wx0a,
                                               const float* __restrict__ b0,
                                               _Float16* __restrict__ zx0){
  int t   = blockIdx.x;        // 512
  int wgg = blockIdx.y;        // 64 (covers 4 wg slices)
  int l = threadIdx.x, q = l>>4, c = l&15;
  floatx4 acc[2][4];
  #pragma unroll
  for (int g=0; g<4; ++g){
    int wg = wgg*4+g;
    float bv = b0[(c>>2)*1024 + wg*4 + (c&3)];
    acc[0][g] = (floatx4){bv,bv,bv,bv};
    acc[1][g] = (floatx4){bv,bv,bv,bv};
  }
  #pragma unroll 4
  for (int ks=0; ks<16; ++ks){
    int kc = ks*4 + q;
    half8 a0 = *(const half8*)(xh + (t*32      + c)*512 + kc*8);
    half8 a1 = *(const half8*)(xh + (t*32 + 16 + c)*512 + kc*8);
    #pragma unroll
    for (int g=0; g<4; ++g){
      int wg = wgg*4+g;
      half8 b = *(const half8*)(wx0a + ((size_t)(wg*64 + kc)*16 + c)*8);
      acc[0][g] = __builtin_amdgcn_mfma_f32_16x16x32_f16(a0,b,acc[0][g],0,0,0);
      acc[1][g] = __builtin_amdgcn_mfma_f32_16x16x32_f16(a1,b,acc[1][g],0,0,0);
    }
  }
  #pragma unroll
  for (int g=0; g<4; ++g){
    int wg = wgg*4+g;
    #pragma unroll
    for (int mt=0; mt<2; ++mt)
      #pragma unroll
      for (int r=0;r<4;++r){
        int m = mt*16 + q*4 + r;
        zx0[((size_t)(t*256 + wg)*32 + m)*16 + c] = (_Float16)acc[mt][g][r];
      }
  }
}

// ---------------- persistent recurrent kernel ------------------------------
// LDS: w0 (Wh0), w1 (Wx1), w2 (Wh1): [128 kc][16 c][8] each = 96 KiB total
#define AF(base, ks)  (*(const half8*)((base) + (ks)*32))
#define BF(w, ks)     (*(const half8*)((w) + (((ks)*4 + q)*16 + c)*8))

// gate exchange + cell update + packed agent-scope store of h (cols wg*4..+3)
__device__ __forceinline__ void gates_store(floatx4 acc, float* cs,
    _Float16* dst, int g, int c, int mt, int q, int wg){
  #pragma unroll
  for (int r=0;r<4;++r){
    float v0 = acc[r];
    float v1 = __shfl_xor(v0, 4, 64);
    float v2 = __shfl_xor(v0, 8, 64);
    float v3 = __shfl_xor(v1, 8, 64);
    float zi = (g==0)?v0:(g==1)?v1:(g==2)?v2:v3;
    float zf = (g==0)?v1:(g==1)?v0:(g==2)?v3:v2;
    float zg = (g==0)?v2:(g==1)?v3:(g==2)?v0:v1;
    float zo = (g==0)?v3:(g==1)?v2:(g==2)?v1:v0;
    float cn = fsig(zf)*cs[r] + fsig(zi)*ftanhf(zg);
    cs[r] = cn;
    float hv = fsig(zo)*ftanhf(cn);
    unsigned hb16 = (unsigned)__builtin_bit_cast(unsigned short, (_Float16)hv);
    unsigned up   = (unsigned)__shfl_xor((int)hb16, 1, 64);
    if (g==0 && (c&1)==0)
      __hip_atomic_store((unsigned*)(dst + (mt*16 + q*4 + r)*1024 + wg*4 + c),
                         hb16 | (up<<16),
                         __ATOMIC_RELAXED, __HIP_MEMORY_SCOPE_AGENT);
  }
}

__global__ __launch_bounds__(128, 1) void lstm_persist(
    const _Float16* __restrict__ wrec, const _Float16* __restrict__ zx0,
    const float* __restrict__ b1g, _Float16* __restrict__ h0a,
    _Float16* __restrict__ h1a, unsigned int* __restrict__ flags)
{
  extern __shared__ _Float16 lds[];
  _Float16* w0  = lds;            // 16384 halves
  _Float16* w1  = lds + 16384;
  _Float16* w2  = lds + 32768;

  const int wg = blockIdx.x, tid = threadIdx.x;
  const int wv = tid>>6, l = tid&63, q = l>>4, c = l&15;
  const int g = (c>>2);           // gate of own column
  const int mt = wv;              // wave0 rows 0-15, wave1 rows 16-31
  const int row = mt*16 + c;      // A-frag row this lane loads
  const int grp = wg >> 3;        // 32 groups of 8

  unsigned int* gcnt = flags + grp*64;        // 256B apart
  unsigned int* root = flags + 2048;          // own line
  unsigned int* go   = flags + 4096;          // go[g2] at 4096 + g2*64

  { // stage this WG's weight slice: 98304 B = 6144 uint4
    const uint4* src = (const uint4*)(wrec + (size_t)wg*49152);
    uint4* dst = (uint4*)lds;
    for (int i=tid; i<6144; i+=128) dst[i] = src[i];
  }
  float c0[4] = {0,0,0,0}, c1[4] = {0,0,0,0};
  const float b1v = b1g[g*1024 + wg*4 + (c&3)];
  __syncthreads();

  // ---------- prologue: A(0): h0(0) = act(Zx0[0]) (h0(-1)=0) ----------
  {
    const _Float16* zsrc = zx0 + ((size_t)wg*32 + mt*16 + q*4)*16 + c;
    floatx4 a;
    a[0]=(float)zsrc[0]; a[1]=(float)zsrc[16]; a[2]=(float)zsrc[32]; a[3]=(float)zsrc[48];
    gates_store(a, c0, h0a, g, c, mt, q, wg);   // t = 0
  }

  for (int t=0; t<512; ++t){
    // prefetch zx0 for A(t+1) (register-resident across the barrier)
    int tn = (t<511) ? t+1 : 511;
    const _Float16* zsrc = zx0 + ((size_t)(tn*256 + wg)*32 + mt*16 + q*4)*16 + c;
    float pz0=(float)zsrc[0], pz1=(float)zsrc[16], pz2=(float)zsrc[32], pz3=(float)zsrc[48];

    __syncthreads();   // drains vmcnt: h0(t)/h1(t-1) stores visible at LLC
    // ---------- device barrier: 32x8 tree + 32-line go broadcast ----------
    if (tid==0){
      unsigned tgt = (unsigned)(t+1);
      unsigned o = __hip_atomic_fetch_add(gcnt, 1u, __ATOMIC_RELAXED,
                                          __HIP_MEMORY_SCOPE_AGENT);
      if (o == 8u*tgt - 1u){
        unsigned r = __hip_atomic_fetch_add(root, 1u, __ATOMIC_RELAXED,
                                            __HIP_MEMORY_SCOPE_AGENT);
        if (r == 32u*tgt - 1u){
          #pragma unroll
          for (int g2=0; g2<32; ++g2)
            __hip_atomic_store(go + g2*64, tgt, __ATOMIC_RELAXED,
                               __HIP_MEMORY_SCOPE_AGENT);
        }
      }
      while (__hip_atomic_load(go + grp*64, __ATOMIC_RELAXED,
                               __HIP_MEMORY_SCOPE_AGENT) < tgt)
        __builtin_amdgcn_s_sleep(1);
    }
    __syncthreads();
    // NO acquire fence: h0a[t]/h1a[t-1] lines are fresh by construction
    // (never cached by any XCD before this read; producers stored uncached
    // to LLC). zx0/weights are read-only; __syncthreads orders compiler+HW.

    // ---------- register-batched loads: all 64 fragments in flight --------
    const _Float16* h0c = h0a + (size_t)t*32768 + row*1024 + q*8;
    const _Float16* h1p = h1a + (size_t)(t-1)*32768 + row*1024 + q*8;
    half8 H1[32], H0[32];
    if (t > 0){
      #pragma unroll
      for (int s=0; s<32; ++s) H1[s] = AF(h1p, s);
    }
    #pragma unroll
    for (int s=0; s<32; ++s) H0[s] = AF(h0c, s);

    // ---------- merged compute: B(t) and A(t+1) ----------
    floatx4 aA0={0,0,0,0}, aA1={0,0,0,0};
    floatx4 aB0={b1v,b1v,b1v,b1v}, aB1={0,0,0,0};
    floatx4 aC0={0,0,0,0}, aC1={0,0,0,0};
    if (t > 0){
      #pragma unroll
      for (int s=0; s<16; ++s){
        aC0 = __builtin_amdgcn_mfma_f32_16x16x32_f16(H1[s],    BF(w2,s),    aC0,0,0,0);
        aC1 = __builtin_amdgcn_mfma_f32_16x16x32_f16(H1[16+s], BF(w2,16+s), aC1,0,0,0);
      }
    }
    #pragma unroll
    for (int s=0; s<16; ++s){
      aB0 = __builtin_amdgcn_mfma_f32_16x16x32_f16(H0[s],    BF(w1,s),    aB0,0,0,0);
      aB1 = __builtin_amdgcn_mfma_f32_16x16x32_f16(H0[16+s], BF(w1,16+s), aB1,0,0,0);
      aA0 = __builtin_amdgcn_mfma_f32_16x16x32_f16(H0[s],    BF(w0,s),    aA0,0,0,0);
      aA1 = __builtin_amdgcn_mfma_f32_16x16x32_f16(H0[16+s], BF(w0,16+s), aA1,0,0,0);
    }
    // B(t): h1(t)
    {
      floatx4 z1 = (aB0+aB1)+(aC0+aC1);
      gates_store(z1, c1, h1a + (size_t)t*32768, g, c, mt, q, wg);
    }
    // A(t+1): h0(t+1)
    if (t < 511){
      floatx4 z0 = aA0+aA1;
      z0[0]+=pz0; z0[1]+=pz1; z0[2]+=pz2; z0[3]+=pz3;
      gates_store(z0, c0, h0a + (size_t)(t+1)*32768, g, c, mt, q, wg);
    }
  }
}

// ---------------- Y = H1 @ Wd + bd -----------------------------------------
__global__ __launch_bounds__(256) void wd_gemm(const _Float16* __restrict__ h1a,
                                               const _Float16* __restrict__ wda,
                                               const float* __restrict__ bd,
                                               float* __restrict__ y){
  int mb = blockIdx.x;   // 512 blocks of 32 rows (rows = t*32+b)
  int nb = blockIdx.y;   // 4 blocks of 128 cols
  int tid = threadIdx.x, wv = tid>>6, l = tid&63, q = l>>4, c = l&15;
  int mt = wv & 1, nh = wv >> 1;
  floatx4 acc[4];
  #pragma unroll
  for (int gg=0; gg<4; ++gg) acc[gg] = (floatx4){0.f,0.f,0.f,0.f};
  const _Float16* arow = h1a + (size_t)(mb*32 + mt*16 + c)*1024;
  #pragma unroll 4
  for (int ks=0; ks<32; ++ks){
    int kc = ks*4 + q;
    half8 a = *(const half8*)(arow + kc*8);
    #pragma unroll
    for (int gg=0; gg<4; ++gg){
      int nt = nb*8 + nh*4 + gg;
      half8 b = *(const half8*)(wda + ((size_t)(nt*128 + kc)*16 + c)*8);
      acc[gg] = __builtin_amdgcn_mfma_f32_16x16x32_f16(a,b,acc[gg],0,0,0);
    }
  }
  #pragma unroll
  for (int gg=0; gg<4; ++gg){
    int o = nb*128 + nh*64 + gg*16 + c;
    float bdv = bd[o];
    #pragma unroll
    for (int r=0;r<4;++r){
      int row = mb*32 + mt*16 + q*4 + r;
      int tt = row >> 5, bb = row & 31;
      y[(size_t)bb*262144 + tt*512 + o] = acc[gg][r] + bdv;
    }
  }
}

// ---------------------------------------------------------------------------
extern "C" void kernel_launch(void* const* d_in, const int* in_sizes, int n_in,
                              void* d_out, int out_size, void* d_ws, size_t ws_size,
                              hipStream_t stream){
  const float* x   = (const float*)d_in[0];
  const float* Wx0 = (const float*)d_in[1];
  const float* Wh0 = (const float*)d_in[2];
  const float* b0  = (const float*)d_in[3];
  const float* Wx1 = (const float*)d_in[4];
  const float* Wh1 = (const float*)d_in[5];
  const float* b1  = (const float*)d_in[6];
  const float* Wd  = (const float*)d_in[7];
  const float* bd  = (const float*)d_in[8];
  float* y = (float*)d_out;
  char* ws = (char*)d_ws;

  _Float16* wrec = (_Float16*)(ws + WREC_OFF);
  _Float16* wx0a = (_Float16*)(ws + WX0_OFF);
  _Float16* wda  = (_Float16*)(ws + WD_OFF);
  _Float16* xh   = (_Float16*)(ws + XH_OFF);
  _Float16* zx0  = (_Float16*)(ws + ZX0_OFF);
  _Float16* h1a  = (_Float16*)(ws + H1_OFF);
  _Float16* h0a  = (_Float16*)(ws + H0_OFF);
  unsigned int* flags = (unsigned int*)(ws + FLAGS_OFF);

  hipMemsetAsync(flags, 0, 24576, stream);
  conv_wrec<<<dim3(6144), dim3(256), 0, stream>>>(Wh0, Wx1, Wh1, wrec);
  conv_wx0 <<<dim3(1024), dim3(256), 0, stream>>>(Wx0, wx0a);
  conv_wd  <<<dim3(256),  dim3(256), 0, stream>>>(Wd, wda);
  conv_x   <<<dim3(8192), dim3(256), 0, stream>>>(x, xh);
  zx0_gemm <<<dim3(512,64), dim3(64), 0, stream>>>(xh, wx0a, b0, zx0);
  hipFuncSetAttribute((const void*)lstm_persist,
                      hipFuncAttributeMaxDynamicSharedMemorySize, 98304);
  lstm_persist<<<dim3(256), dim3(128), 98304, stream>>>(wrec, zx0, b1, h0a, h1a, flags);
  wd_gemm  <<<dim3(512,4), dim3(256), 0, stream>>>(h1a, wda, bd, y);
}